// Round 17
// baseline (108.906 us; speedup 1.0000x reference)
//
#include <hip/hip_runtime.h>
#include <math.h>

#define BATCH 4
#define SEQ   4096
#define DIM   1024
#define HEAD  64
#define MROWS (BATCH*SEQ)   // 16384
#define NCOL  192
#define WST   1040          // repacked W row stride (elements)
#define KT    64
#define QBLK  64            // flashmm q-rows per block (proven locality)
#define BK2   64            // qkvmm K-step
#define NIT2  (DIM / BK2)   // 16

typedef __attribute__((ext_vector_type(8))) short short8;
typedef __attribute__((ext_vector_type(4))) float f32x4;

static __device__ __forceinline__ unsigned short f2b(float f) {
    union { float f; unsigned u; } v; v.f = f;
    return (unsigned short)((v.u + 0x7FFFu + ((v.u >> 16) & 1u)) >> 16);
}
// hardware RTNE pack: low16 = bf16(a), high16 = bf16(b)
static __device__ __forceinline__ unsigned cvtpk(float a, float b) {
    unsigned r;
    asm("v_cvt_pk_bf16_f32 %0, %1, %2" : "=v"(r) : "v"(a), "v"(b));
    return r;
}

// ---------------- Kernel 0: weight convert fp32 -> bf16, stride-1040 repack ----------------
#define QSC (0.125f * 1.4426950408889634f)   // fold 1/sqrt(64) * log2(e): exp2 domain
__global__ __launch_bounds__(256) void wconv_kernel(
    const float* __restrict__ wq, const float* __restrict__ bq,
    const float* __restrict__ wk, const float* __restrict__ bk,
    const float* __restrict__ wv, const float* __restrict__ bv,
    unsigned short* __restrict__ Wb, float* __restrict__ biasAll)
{
    int idx = blockIdx.x * 256 + threadIdx.x;
    int e   = idx * 4;
    int row = e >> 10;
    int col = e & 1023;
    const float* src = (row < 64) ? wq : (row < 128) ? wk : wv;
    float s = (row < 64) ? QSC : 1.0f;
    float4 g = *(const float4*)&src[(size_t)(row & 63) * DIM + col];
    ushort4 o;
    o.x = f2b(g.x * s); o.y = f2b(g.y * s); o.z = f2b(g.z * s); o.w = f2b(g.w * s);
    *(ushort4*)&Wb[(size_t)row * WST + col] = o;
    if (idx < 192) {
        const float* bs = (idx < 64) ? bq : (idx < 128) ? bk : bv;
        biasAll[idx] = bs[idx & 63] * ((idx < 64) ? QSC : 1.0f);
    }
}

// ---------------- Kernel 1: fused QKV projection (R13-exact, best profiled) ----------------
__global__ __launch_bounds__(256, 4) void qkvmm_kernel(
    const float* __restrict__ x, const unsigned short* __restrict__ Wb,
    const float* __restrict__ biasAll,
    unsigned short* __restrict__ qout, unsigned short* __restrict__ kout,
    unsigned short* __restrict__ vtout)
{
    __shared__ unsigned short xs[32 * BK2];     // 4 KB
    __shared__ unsigned short ws[NCOL * BK2];   // 24 KB

    const int tid  = threadIdx.x;
    const int m0   = blockIdx.x * 32;
    const int bb   = m0 >> 12;
    const int lane = tid & 63;
    const int w    = tid >> 6;
    const int lr   = lane & 15;
    const int lg   = lane >> 4;
    const int mrow  = (w >> 1) * 16;
    const int nbase = (w & 1) * 6;

    int wrow[6], wc[6];
    #pragma unroll
    for (int j = 0; j < 6; ++j) { int L = j * 256 + tid; wrow[j] = L >> 3; wc[j] = L & 7; }
    const int xr = tid >> 2, xq = tid & 3;

    f32x4 acc[6];
    #pragma unroll
    for (int nt = 0; nt < 6; ++nt) acc[nt] = (f32x4){0.f, 0.f, 0.f, 0.f};

    float4 xg[4];
    short8 wg[6];

    auto LOADR = [&](int ko) {
        if (tid < 128) {
            const float* xp = &x[(size_t)(m0 + xr) * DIM + ko + xq * 16];
            xg[0] = *(const float4*)xp;       xg[1] = *(const float4*)(xp + 4);
            xg[2] = *(const float4*)(xp + 8); xg[3] = *(const float4*)(xp + 12);
        }
        #pragma unroll
        for (int j = 0; j < 6; ++j)
            wg[j] = *(const short8*)&Wb[(size_t)wrow[j] * WST + ko + wc[j] * 8];
    };
    auto WRITE = [&]() {
        if (tid < 128) {
            uint4 c0, c1;
            c0.x = cvtpk(xg[0].x, xg[0].y); c0.y = cvtpk(xg[0].z, xg[0].w);
            c0.z = cvtpk(xg[1].x, xg[1].y); c0.w = cvtpk(xg[1].z, xg[1].w);
            c1.x = cvtpk(xg[2].x, xg[2].y); c1.y = cvtpk(xg[2].z, xg[2].w);
            c1.z = cvtpk(xg[3].x, xg[3].y); c1.w = cvtpk(xg[3].z, xg[3].w);
            *(uint4*)&xs[xr * BK2 + (((2 * xq)     ^ (xr & 7)) * 8)] = c0;
            *(uint4*)&xs[xr * BK2 + (((2 * xq + 1) ^ (xr & 7)) * 8)] = c1;
        }
        #pragma unroll
        for (int j = 0; j < 6; ++j)
            *(short8*)&ws[wrow[j] * BK2 + ((wc[j] ^ (wrow[j] & 7)) * 8)] = wg[j];
    };

    LOADR(0);
    for (int it = 0; it < NIT2; ++it) {
        __syncthreads();
        WRITE();
        __syncthreads();
        if (it + 1 < NIT2) LOADR((it + 1) * BK2);

        __builtin_amdgcn_s_setprio(1);
        #pragma unroll
        for (int h = 0; h < 2; ++h) {
            const int arow = mrow + lr;
            short8 af = *(const short8*)&xs[arow * BK2 + (((h * 4 + lg) ^ (arow & 7)) * 8)];
            #pragma unroll
            for (int nt = 0; nt < 6; ++nt) {
                int n = (nbase + nt) * 16 + lr;
                short8 bf = *(const short8*)&ws[n * BK2 + (((h * 4 + lg) ^ (n & 7)) * 8)];
                acc[nt] = __builtin_amdgcn_mfma_f32_16x16x32_bf16(af, bf, acc[nt], 0, 0, 0);
            }
        }
        __builtin_amdgcn_s_setprio(0);
    }

    #pragma unroll
    for (int nt = 0; nt < 6; ++nt) {
        int gn = (nbase + nt) * 16 + lr;
        float bv_ = biasAll[gn];
        #pragma unroll
        for (int r = 0; r < 4; ++r) {
            int grow = m0 + mrow + lg * 4 + r;
            unsigned short val = f2b(acc[nt][r] + bv_);
            if (gn < 64)       qout[(size_t)grow * HEAD + gn] = val;
            else if (gn < 128) kout[(size_t)grow * HEAD + gn - 64] = val;
            else {
                int t = (m0 & 4095) + mrow + lg * 4 + r;
                vtout[((size_t)bb * HEAD + gn - 128) * SEQ + t] = val;
            }
        }
    }
}

// ---------------- Kernel 2: flash attention — K fragments direct from global ----------------
// grid (SEQ/QBLK, BATCH, KS), block 256 (4 waves). Lane owns q-row lr, keys lg-sliced.
// K is NOT staged in LDS: each wave reads its K fragments straight from kb (L1/L2-hot,
// bit-identical values). DS ops per wave-tile drop 28 -> 18 (-36%): the LDS pipe was
// the measured bottleneck (~1340 cyc/block-tile of b128 traffic).
__global__ __launch_bounds__(256, 4) void flashmm_kernel(
    const unsigned short* __restrict__ qb, const unsigned short* __restrict__ kb,
    const unsigned short* __restrict__ vt, const int* __restrict__ mask,
    float* __restrict__ opart, float* __restrict__ mpart, float* __restrict__ lpart,
    int nsplit)
{
    const int b  = blockIdx.y;
    const int t0 = blockIdx.x * QBLK;
    const int z  = blockIdx.z;
    const int tid  = threadIdx.x;
    const int lane = tid & 63;
    const int w    = tid >> 6;
    const int lr = lane & 15;
    const int lg = lane >> 4;
    const int span = SEQ / nsplit;
    const int s_begin = z * span, s_end = s_begin + span;

    __shared__ unsigned short vt_l[HEAD * KT];        // 8 KB
    __shared__ unsigned short ps_l[4][16 * KT];       // 8 KB
    __shared__ float mkf[KT];

    const unsigned short* qrow = qb + ((size_t)(b * SEQ + t0 + w * 16 + lr)) * HEAD;
    const short8 qf0 = *(const short8*)(qrow + lg * 8);
    const short8 qf1 = *(const short8*)(qrow + 32 + lg * 8);

    f32x4 acc_o[4];
    #pragma unroll
    for (int nt = 0; nt < 4; ++nt) acc_o[nt] = (f32x4){0.f, 0.f, 0.f, 0.f};
    float m_r = -INFINITY, l_r = 0.f;

    short8 vg[2];
    float mgf = 0.f;

    auto LOADR = [&](int st) {
        #pragma unroll
        for (int i = 0; i < 2; ++i) {
            int c   = tid + i * 256;
            int row = c >> 3;
            int h0  = (c & 7) * 8;
            vg[i] = *(const short8*)(vt + ((size_t)(b * HEAD + row)) * SEQ + st + h0);
        }
        if (tid < KT) mgf = (mask[(size_t)b * SEQ + st + tid] != 0) ? 0.f : -1e9f;
    };
    auto WRITE = [&]() {
        #pragma unroll
        for (int i = 0; i < 2; ++i) {
            int c   = tid + i * 256;
            int row = c >> 3;
            int h0  = (c & 7) * 8;
            *(short8*)&vt_l[row * KT + (h0 ^ ((row & 7) << 3))] = vg[i];
        }
        if (tid < KT) mkf[tid] = mgf;
    };

    LOADR(s_begin);
    for (int st = s_begin; st < s_end; st += KT) {
        __syncthreads();
        WRITE();
        __syncthreads();
        if (st + KT < s_end) LOADR(st + KT);

        // ---- QK^T swapped: K fragments direct from global (L1/L2-hot) ----
        const unsigned short* kbt = kb + ((size_t)(b * SEQ + st)) * HEAD;
        f32x4 sT[4];
        __builtin_amdgcn_s_setprio(1);
        #pragma unroll
        for (int ct = 0; ct < 4; ++ct) {
            const unsigned short* kr = kbt + (size_t)(ct * 16 + lr) * HEAD + lg * 8;
            short8 kf0 = *(const short8*)(kr);
            short8 kf1 = *(const short8*)(kr + 32);
            f32x4 zz = (f32x4){0.f, 0.f, 0.f, 0.f};
            zz = __builtin_amdgcn_mfma_f32_16x16x32_bf16(kf0, qf0, zz, 0, 0, 0);
            zz = __builtin_amdgcn_mfma_f32_16x16x32_bf16(kf1, qf1, zz, 0, 0, 0);
            sT[ct] = zz;
        }
        __builtin_amdgcn_s_setprio(0);

        #pragma unroll
        for (int ct = 0; ct < 4; ++ct) {
            f32x4 mb = *(const f32x4*)&mkf[ct * 16 + lg * 4];
            sT[ct][0] += mb[0]; sT[ct][1] += mb[1];
            sT[ct][2] += mb[2]; sT[ct][3] += mb[3];
        }

        float mx = sT[0][0];
        #pragma unroll
        for (int ct = 0; ct < 4; ++ct)
            #pragma unroll
            for (int r = 0; r < 4; ++r) mx = fmaxf(mx, sT[ct][r]);
        mx = fmaxf(mx, __shfl_xor(mx, 16));
        mx = fmaxf(mx, __shfl_xor(mx, 32));

        bool defer = __all(mx <= m_r + 8.f);
        float base = defer ? m_r : fmaxf(m_r, mx);

        float rs = 0.f;
        #pragma unroll
        for (int ct = 0; ct < 4; ++ct)
            #pragma unroll
            for (int r = 0; r < 4; ++r) {
                float p = __builtin_amdgcn_exp2f(sT[ct][r] - base);
                sT[ct][r] = p;
                rs += p;
            }
        rs += __shfl_xor(rs, 16);
        rs += __shfl_xor(rs, 32);

        if (defer) {
            l_r += rs;
        } else {
            float sf = __builtin_amdgcn_exp2f(m_r - base);
            l_r = l_r * sf + rs;
            m_r = base;
            #pragma unroll
            for (int r = 0; r < 4; ++r) {
                float sfr = __shfl(sf, lg * 4 + r);
                #pragma unroll
                for (int nt = 0; nt < 4; ++nt) acc_o[nt][r] *= sfr;
            }
        }

        #pragma unroll
        for (int ct = 0; ct < 4; ++ct) {
            uint2 pk;
            pk.x = cvtpk(sT[ct][0], sT[ct][1]);
            pk.y = cvtpk(sT[ct][2], sT[ct][3]);
            *(uint2*)&ps_l[w][lr * KT + ((ct * 16 + lg * 4) ^ ((lr & 7) << 3))] = pk;
        }

        __builtin_amdgcn_s_setprio(1);
        #pragma unroll
        for (int kk = 0; kk < 2; ++kk) {
            int s0 = kk * 32 + lg * 8;
            short8 pf = *(const short8*)&ps_l[w][lr * KT + (s0 ^ ((lr & 7) << 3))];
            #pragma unroll
            for (int nt = 0; nt < 4; ++nt) {
                int hrow = nt * 16 + lr;
                short8 vf = *(const short8*)&vt_l[hrow * KT + (s0 ^ ((hrow & 7) << 3))];
                acc_o[nt] = __builtin_amdgcn_mfma_f32_16x16x32_bf16(pf, vf, acc_o[nt], 0, 0, 0);
            }
        }
        __builtin_amdgcn_s_setprio(0);
    }

    const size_t rbase = (size_t)z * MROWS + (size_t)b * SEQ + t0 + w * 16;
    const size_t obase = rbase * HEAD;
    #pragma unroll
    for (int nt = 0; nt < 4; ++nt)
        #pragma unroll
        for (int r = 0; r < 4; ++r) {
            int R = lg * 4 + r;
            opart[obase + (size_t)R * HEAD + nt * 16 + lr] = acc_o[nt][r];
        }
    if (lg == 0) {
        mpart[rbase + lr] = m_r;
        lpart[rbase + lr] = l_r;
    }
}

// ---------------- Kernel 3: split combine + normalize (exp2 domain) ----------------
__global__ __launch_bounds__(256) void combine_kernel(
    const float* __restrict__ op, const float* __restrict__ mp,
    const float* __restrict__ lp, float* __restrict__ out, int nsplit)
{
    int idx = blockIdx.x * 256 + threadIdx.x;
    int row = idx >> 4;
    int h4  = (idx & 15) * 4;
    float mstar = -INFINITY;
    for (int s = 0; s < nsplit; ++s)
        mstar = fmaxf(mstar, mp[(size_t)s * MROWS + row]);
    float L = 0.f;
    float ax = 0.f, ay = 0.f, az = 0.f, aw = 0.f;
    for (int s = 0; s < nsplit; ++s) {
        float wgt = __builtin_amdgcn_exp2f(mp[(size_t)s * MROWS + row] - mstar);
        L += lp[(size_t)s * MROWS + row] * wgt;
        float4 o = *(const float4*)&op[((size_t)s * MROWS + row) * HEAD + h4];
        ax += o.x * wgt; ay += o.y * wgt; az += o.z * wgt; aw += o.w * wgt;
    }
    float r = 1.f / L;
    float4 res; res.x = ax * r; res.y = ay * r; res.z = az * r; res.w = aw * r;
    *(float4*)&out[(size_t)row * HEAD + h4] = res;
}

extern "C" void kernel_launch(void* const* d_in, const int* in_sizes, int n_in,
                              void* d_out, int out_size, void* d_ws, size_t ws_size,
                              hipStream_t stream) {
    const float* x    = (const float*)d_in[0];
    const int*   mask = (const int*)d_in[1];
    const float* wq   = (const float*)d_in[2];
    const float* bq   = (const float*)d_in[3];
    const float* wk   = (const float*)d_in[4];
    const float* bk   = (const float*)d_in[5];
    const float* wv   = (const float*)d_in[6];
    const float* bv   = (const float*)d_in[7];
    float* out = (float*)d_out;
    (void)in_sizes; (void)n_in; (void)out_size;

    const size_t NB = (size_t)MROWS * HEAD;
    unsigned short* qw  = (unsigned short*)d_ws;
    unsigned short* kw  = qw + NB;
    unsigned short* vtw = kw + NB;
    unsigned short* Wb  = vtw + NB;                       // 192 x 1040 bf16
    float* biasAll = (float*)(Wb + (size_t)NCOL * WST);
    float* mpart   = biasAll + 192;

    const size_t base = 3 * NB * 2 + (size_t)NCOL * WST * 2 + 192 * 4;
    const size_t per  = (size_t)MROWS * 8 + NB * 4;
    int KS = 1;
    if      (ws_size >= base + 4 * per) KS = 4;
    else if (ws_size >= base + 2 * per) KS = 2;

    float* lpart = mpart + (size_t)KS * MROWS;
    float* opart = lpart + (size_t)KS * MROWS;

    wconv_kernel<<<dim3(192), 256, 0, stream>>>(wq, bq, wk, bk, wv, bv, Wb, biasAll);
    qkvmm_kernel<<<dim3(MROWS / 32), 256, 0, stream>>>(x, Wb, biasAll, qw, kw, vtw);
    flashmm_kernel<<<dim3(SEQ / QBLK, BATCH, KS), 256, 0, stream>>>(qw, kw, vtw, mask,
                                                                    opart, mpart, lpart, KS);
    combine_kernel<<<dim3(MROWS * 16 / 256), 256, 0, stream>>>(opart, mpart, lpart, out, KS);
}

// Round 18
// 71.407 us; speedup vs baseline: 1.5251x; 1.5251x over previous
//
#include <hip/hip_runtime.h>
#include <math.h>

#define BATCH 4
#define SEQ   4096
#define DIM   1024
#define HEAD  64
#define MROWS (BATCH*SEQ)   // 16384
#define KT    64
#define QBLK  64            // flashmm: known-good config

typedef __attribute__((ext_vector_type(8))) short short8;
typedef __attribute__((ext_vector_type(4))) float f32x4;

static __device__ __forceinline__ unsigned short f2b(float f) {
    union { float f; unsigned u; } v; v.f = f;
    return (unsigned short)((v.u + 0x7FFFu + ((v.u >> 16) & 1u)) >> 16);
}
// hardware RTNE pack: low16 = bf16(a), high16 = bf16(b)
static __device__ __forceinline__ unsigned cvtpk(float a, float b) {
    unsigned r;
    asm("v_cvt_pk_bf16_f32 %0, %1, %2" : "=v"(r) : "v"(a), "v"(b));
    return r;
}
// LDS-only fence + raw barrier: drains ds ops (lgkmcnt) but leaves global loads in flight.
static __device__ __forceinline__ void lds_barrier() {
    asm volatile("s_waitcnt lgkmcnt(0)" ::: "memory");
    __builtin_amdgcn_s_barrier();
}

// ---------------- Kernel 0: weight convert fp32 -> bf16 [192][1024] ----------------
#define QSC (0.125f * 1.4426950408889634f)   // fold 1/sqrt(64) * log2(e): exp2 domain
__global__ __launch_bounds__(256) void wconv_kernel(
    const float* __restrict__ wq, const float* __restrict__ bq,
    const float* __restrict__ wk, const float* __restrict__ bk,
    const float* __restrict__ wv, const float* __restrict__ bv,
    unsigned short* __restrict__ Wb, float* __restrict__ biasAll)
{
    int idx = blockIdx.x * 256 + threadIdx.x;
    int e   = idx * 4;
    int row = e >> 10;
    int col = e & 1023;
    const float* src = (row < 64) ? wq : (row < 128) ? wk : wv;
    float s = (row < 64) ? QSC : 1.0f;
    float4 g = *(const float4*)&src[(size_t)(row & 63) * DIM + col];
    ushort4 o;
    o.x = f2b(g.x * s); o.y = f2b(g.y * s); o.z = f2b(g.z * s); o.w = f2b(g.w * s);
    *(ushort4*)&Wb[e] = o;
    if (idx < 192) {
        const float* bs = (idx < 64) ? bq : (idx < 128) ? bk : bv;
        biasAll[idx] = bs[idx & 63] * ((idx < 64) ? QSC : 1.0f);
    }
}

// ---------------- Kernel 1: fused QKV projection, bf16 MFMA ----------------
// M=16384, N=192, K=1024. BM=32, BK=32, grid 512, block 256 (4 waves: 2M x 2N).
// Reg-staged double-buffer, 3-set rotation, lgkmcnt-only barriers (global loads
// survive the barrier). Session-best composition: benched 71.5us total.
#define NIT (DIM / 32)
__global__ __launch_bounds__(256) void qkvmm_kernel(
    const float* __restrict__ x, const unsigned short* __restrict__ Wb,
    const float* __restrict__ biasAll,
    unsigned short* __restrict__ qout, unsigned short* __restrict__ kout,
    unsigned short* __restrict__ vtout)
{
    __shared__ unsigned short xs[2][32 * 32];
    __shared__ unsigned short ws[2][192 * 32];

    const int tid  = threadIdx.x;
    const int m0   = blockIdx.x * 32;
    const int bb   = m0 >> 12;
    const int lane = tid & 63;
    const int w    = tid >> 6;
    const int lr   = lane & 15;
    const int lg   = lane >> 4;
    const int mrow  = (w >> 1) * 16;
    const int nbase = (w & 1) * 6;

    const int sxrow = tid >> 2, sxlg = tid & 3;     // x staging (tid<128)
    int wn[3], wlg[3];                               // W staging (all threads, 3 chunks)
    #pragma unroll
    for (int i = 0; i < 3; ++i) { int idx = tid + i * 256; wn[i] = idx >> 2; wlg[i] = idx & 3; }

    f32x4 acc[6];
    #pragma unroll
    for (int nt = 0; nt < 6; ++nt) acc[nt] = (f32x4){0.f, 0.f, 0.f, 0.f};

    // 3 register staging sets
    float4 xg0[3], xg1[3];
    short8 wg0[3], wg1[3], wg2[3];

    auto LOADR = [&](int ko, int s) {
        if (tid < 128) {
            const float* xp = &x[(size_t)(m0 + sxrow) * DIM + ko + sxlg * 8];
            xg0[s] = *(const float4*)xp;
            xg1[s] = *(const float4*)(xp + 4);
        }
        wg0[s] = *(const short8*)&Wb[(size_t)wn[0] * DIM + ko + wlg[0] * 8];
        wg1[s] = *(const short8*)&Wb[(size_t)wn[1] * DIM + ko + wlg[1] * 8];
        wg2[s] = *(const short8*)&Wb[(size_t)wn[2] * DIM + ko + wlg[2] * 8];
    };
    auto WRITE = [&](int buf, int s) {
        if (tid < 128) {
            uint4 c;
            c.x = cvtpk(xg0[s].x, xg0[s].y); c.y = cvtpk(xg0[s].z, xg0[s].w);
            c.z = cvtpk(xg1[s].x, xg1[s].y); c.w = cvtpk(xg1[s].z, xg1[s].w);
            *(uint4*)&xs[buf][sxrow * 32 + ((sxlg * 8) ^ ((sxrow & 3) * 8))] = c;
        }
        *(short8*)&ws[buf][wn[0] * 32 + ((wlg[0] * 8) ^ ((wn[0] & 3) * 8))] = wg0[s];
        *(short8*)&ws[buf][wn[1] * 32 + ((wlg[1] * 8) ^ ((wn[1] & 3) * 8))] = wg1[s];
        *(short8*)&ws[buf][wn[2] * 32 + ((wlg[2] * 8) ^ ((wn[2] & 3) * 8))] = wg2[s];
    };

    LOADR(0, 0); LOADR(32, 1); LOADR(64, 2);
    WRITE(0, 0);                 // counted vmcnt on set0 regs only (sets 1,2 stay in flight)
    lds_barrier();

    #pragma unroll
    for (int it = 0; it < NIT; ++it) {
        const int cur = it & 1;
        if (it + 3 < NIT) LOADR((it + 3) * 32, (it + 3) % 3);   // issue-early
        if (it + 1 < NIT) WRITE(cur ^ 1, (it + 1) % 3);         // write-late (1 iter gap)

        const int arow = mrow + lr;
        short8 af = *(const short8*)&xs[cur][arow * 32 + ((lg * 8) ^ ((arow & 3) * 8))];
        #pragma unroll
        for (int nt = 0; nt < 6; ++nt) {
            int n = (nbase + nt) * 16 + lr;
            short8 bf = *(const short8*)&ws[cur][n * 32 + ((lg * 8) ^ ((n & 3) * 8))];
            acc[nt] = __builtin_amdgcn_mfma_f32_16x16x32_bf16(af, bf, acc[nt], 0, 0, 0);
        }
        lds_barrier();           // drains ds reads+writes only; global loads survive
    }

    // ---- epilogue: bias + bf16, scatter to q / k / vt ----
    #pragma unroll
    for (int nt = 0; nt < 6; ++nt) {
        int gn = (nbase + nt) * 16 + lr;
        float bv_ = biasAll[gn];
        #pragma unroll
        for (int r = 0; r < 4; ++r) {
            int grow = m0 + mrow + lg * 4 + r;
            unsigned short val = f2b(acc[nt][r] + bv_);
            if (gn < 64)       qout[(size_t)grow * HEAD + gn] = val;
            else if (gn < 128) kout[(size_t)grow * HEAD + gn - 64] = val;
            else {
                int t = (m0 & 4095) + mrow + lg * 4 + r;
                vtout[((size_t)bb * HEAD + gn - 128) * SEQ + t] = val;
            }
        }
    }
}

// ---------------- Kernel 2: flash attention, swapped-QK^T bf16 MFMA ----------------
// grid (SEQ/QBLK, BATCH, KS), block 256 (4 waves). Lane owns q-row lr, keys lg-sliced.
__global__ __launch_bounds__(256, 4) void flashmm_kernel(
    const unsigned short* __restrict__ qb, const unsigned short* __restrict__ kb,
    const unsigned short* __restrict__ vt, const int* __restrict__ mask,
    float* __restrict__ opart, float* __restrict__ mpart, float* __restrict__ lpart,
    int nsplit)
{
    const int b  = blockIdx.y;
    const int t0 = blockIdx.x * QBLK;
    const int z  = blockIdx.z;
    const int tid  = threadIdx.x;
    const int lane = tid & 63;
    const int w    = tid >> 6;
    const int lr = lane & 15;
    const int lg = lane >> 4;
    const int span = SEQ / nsplit;
    const int s_begin = z * span, s_end = s_begin + span;

    __shared__ unsigned short ks_l[KT * HEAD];
    __shared__ unsigned short vt_l[HEAD * KT];
    __shared__ unsigned short ps_l[4][16 * KT];
    __shared__ float mkf[KT];

    const unsigned short* qrow = qb + ((size_t)(b * SEQ + t0 + w * 16 + lr)) * HEAD;
    const short8 qf0 = *(const short8*)(qrow + lg * 8);
    const short8 qf1 = *(const short8*)(qrow + 32 + lg * 8);

    f32x4 acc_o[4];
    #pragma unroll
    for (int nt = 0; nt < 4; ++nt) acc_o[nt] = (f32x4){0.f, 0.f, 0.f, 0.f};
    float m_r = -INFINITY, l_r = 0.f;

    short8 kg[2], vg[2];
    float mgf = 0.f;

    auto LOADR = [&](int st) {
        #pragma unroll
        for (int i = 0; i < 2; ++i) {
            int c   = tid + i * 256;
            int row = c >> 3;
            int h0  = (c & 7) * 8;
            kg[i] = *(const short8*)(kb + ((size_t)(b * SEQ + st + row)) * HEAD + h0);
            vg[i] = *(const short8*)(vt + ((size_t)(b * HEAD + row)) * SEQ + st + h0);
        }
        if (tid < KT) mgf = (mask[(size_t)b * SEQ + st + tid] != 0) ? 0.f : -1e9f;
    };
    auto WRITE = [&]() {
        #pragma unroll
        for (int i = 0; i < 2; ++i) {
            int c   = tid + i * 256;
            int row = c >> 3;
            int h0  = (c & 7) * 8;
            *(short8*)&ks_l[row * HEAD + (h0 ^ ((row & 7) << 3))] = kg[i];
            *(short8*)&vt_l[row * KT + (h0 ^ ((row & 7) << 3))] = vg[i];
        }
        if (tid < KT) mkf[tid] = mgf;
    };

    LOADR(s_begin);
    for (int st = s_begin; st < s_end; st += KT) {
        __syncthreads();
        WRITE();
        __syncthreads();
        if (st + KT < s_end) LOADR(st + KT);

        f32x4 sT[4];
        __builtin_amdgcn_s_setprio(1);
        #pragma unroll
        for (int ct = 0; ct < 4; ++ct) {
            int krow = ct * 16 + lr;
            short8 kf0 = *(const short8*)&ks_l[krow * HEAD + ((lg * 8) ^ ((krow & 7) << 3))];
            short8 kf1 = *(const short8*)&ks_l[krow * HEAD + ((32 + lg * 8) ^ ((krow & 7) << 3))];
            f32x4 zz = (f32x4){0.f, 0.f, 0.f, 0.f};
            zz = __builtin_amdgcn_mfma_f32_16x16x32_bf16(kf0, qf0, zz, 0, 0, 0);
            zz = __builtin_amdgcn_mfma_f32_16x16x32_bf16(kf1, qf1, zz, 0, 0, 0);
            sT[ct] = zz;
        }
        __builtin_amdgcn_s_setprio(0);

        #pragma unroll
        for (int ct = 0; ct < 4; ++ct) {
            f32x4 mb = *(const f32x4*)&mkf[ct * 16 + lg * 4];
            sT[ct][0] += mb[0]; sT[ct][1] += mb[1];
            sT[ct][2] += mb[2]; sT[ct][3] += mb[3];
        }

        float mx = sT[0][0];
        #pragma unroll
        for (int ct = 0; ct < 4; ++ct)
            #pragma unroll
            for (int r = 0; r < 4; ++r) mx = fmaxf(mx, sT[ct][r]);
        mx = fmaxf(mx, __shfl_xor(mx, 16));
        mx = fmaxf(mx, __shfl_xor(mx, 32));

        bool defer = __all(mx <= m_r + 8.f);
        float base = defer ? m_r : fmaxf(m_r, mx);

        float rs = 0.f;
        #pragma unroll
        for (int ct = 0; ct < 4; ++ct)
            #pragma unroll
            for (int r = 0; r < 4; ++r) {
                float p = __builtin_amdgcn_exp2f(sT[ct][r] - base);
                sT[ct][r] = p;
                rs += p;
            }
        rs += __shfl_xor(rs, 16);
        rs += __shfl_xor(rs, 32);

        if (defer) {
            l_r += rs;
        } else {
            float sf = __builtin_amdgcn_exp2f(m_r - base);
            l_r = l_r * sf + rs;
            m_r = base;
            #pragma unroll
            for (int r = 0; r < 4; ++r) {
                float sfr = __shfl(sf, lg * 4 + r);
                #pragma unroll
                for (int nt = 0; nt < 4; ++nt) acc_o[nt][r] *= sfr;
            }
        }

        #pragma unroll
        for (int ct = 0; ct < 4; ++ct) {
            uint2 pk;
            pk.x = cvtpk(sT[ct][0], sT[ct][1]);
            pk.y = cvtpk(sT[ct][2], sT[ct][3]);
            *(uint2*)&ps_l[w][lr * KT + ((ct * 16 + lg * 4) ^ ((lr & 7) << 3))] = pk;
        }

        __builtin_amdgcn_s_setprio(1);
        #pragma unroll
        for (int kk = 0; kk < 2; ++kk) {
            int s0 = kk * 32 + lg * 8;
            short8 pf = *(const short8*)&ps_l[w][lr * KT + (s0 ^ ((lr & 7) << 3))];
            #pragma unroll
            for (int nt = 0; nt < 4; ++nt) {
                int hrow = nt * 16 + lr;
                short8 vf = *(const short8*)&vt_l[hrow * KT + (s0 ^ ((hrow & 7) << 3))];
                acc_o[nt] = __builtin_amdgcn_mfma_f32_16x16x32_bf16(pf, vf, acc_o[nt], 0, 0, 0);
            }
        }
        __builtin_amdgcn_s_setprio(0);
    }

    const size_t rbase = (size_t)z * MROWS + (size_t)b * SEQ + t0 + w * 16;
    const size_t obase = rbase * HEAD;
    #pragma unroll
    for (int nt = 0; nt < 4; ++nt)
        #pragma unroll
        for (int r = 0; r < 4; ++r) {
            int R = lg * 4 + r;
            opart[obase + (size_t)R * HEAD + nt * 16 + lr] = acc_o[nt][r];
        }
    if (lg == 0) {
        mpart[rbase + lr] = m_r;
        lpart[rbase + lr] = l_r;
    }
}

// ---------------- Kernel 3: split combine + normalize (exp2 domain) ----------------
__global__ __launch_bounds__(256) void combine_kernel(
    const float* __restrict__ op, const float* __restrict__ mp,
    const float* __restrict__ lp, float* __restrict__ out, int nsplit)
{
    int idx = blockIdx.x * 256 + threadIdx.x;
    int row = idx >> 4;
    int h4  = (idx & 15) * 4;
    float mstar = -INFINITY;
    for (int s = 0; s < nsplit; ++s)
        mstar = fmaxf(mstar, mp[(size_t)s * MROWS + row]);
    float L = 0.f;
    float ax = 0.f, ay = 0.f, az = 0.f, aw = 0.f;
    for (int s = 0; s < nsplit; ++s) {
        float wgt = __builtin_amdgcn_exp2f(mp[(size_t)s * MROWS + row] - mstar);
        L += lp[(size_t)s * MROWS + row] * wgt;
        float4 o = *(const float4*)&op[((size_t)s * MROWS + row) * HEAD + h4];
        ax += o.x * wgt; ay += o.y * wgt; az += o.z * wgt; aw += o.w * wgt;
    }
    float r = 1.f / L;
    float4 res; res.x = ax * r; res.y = ay * r; res.z = az * r; res.w = aw * r;
    *(float4*)&out[(size_t)row * HEAD + h4] = res;
}

extern "C" void kernel_launch(void* const* d_in, const int* in_sizes, int n_in,
                              void* d_out, int out_size, void* d_ws, size_t ws_size,
                              hipStream_t stream) {
    const float* x    = (const float*)d_in[0];
    const int*   mask = (const int*)d_in[1];
    const float* wq   = (const float*)d_in[2];
    const float* bq   = (const float*)d_in[3];
    const float* wk   = (const float*)d_in[4];
    const float* bk   = (const float*)d_in[5];
    const float* wv   = (const float*)d_in[6];
    const float* bv   = (const float*)d_in[7];
    float* out = (float*)d_out;
    (void)in_sizes; (void)n_in; (void)out_size;

    const size_t NB = (size_t)MROWS * HEAD;
    unsigned short* qw  = (unsigned short*)d_ws;
    unsigned short* kw  = qw + NB;
    unsigned short* vtw = kw + NB;
    unsigned short* Wb  = vtw + NB;
    float* biasAll = (float*)(Wb + (size_t)192 * DIM);
    float* mpart   = biasAll + 192;

    const size_t base = 3 * NB * 2 + (size_t)192 * DIM * 2 + 192 * 4;
    const size_t per  = (size_t)MROWS * 8 + NB * 4;
    int KS = 1;
    if      (ws_size >= base + 4 * per) KS = 4;
    else if (ws_size >= base + 2 * per) KS = 2;

    float* lpart = mpart + (size_t)KS * MROWS;
    float* opart = lpart + (size_t)KS * MROWS;

    wconv_kernel<<<dim3(192), 256, 0, stream>>>(wq, bq, wk, bk, wv, bv, Wb, biasAll);
    qkvmm_kernel<<<dim3(MROWS / 32), 256, 0, stream>>>(x, Wb, biasAll, qw, kw, vtw);
    flashmm_kernel<<<dim3(SEQ / QBLK, BATCH, KS), 256, 0, stream>>>(qw, kw, vtw, mask,
                                                                    opart, mpart, lpart, KS);
    combine_kernel<<<dim3(MROWS * 16 / 256), 256, 0, stream>>>(opart, mpart, lpart, out, KS);
}